// Round 2
// baseline (118.976 us; speedup 1.0000x reference)
//
#include <hip/hip_runtime.h>
#include <math.h>

// Problem dims (fixed by setup_inputs): B=2, D=64, H=96, W=96, fp32.
#define BDIM 2
#define DDIM 64
#define HDIM 96
#define WDIM 96
#define HW   (HDIM * WDIM)          // 9216
#define DHW  (DDIM * HDIM * WDIM)   // 589824
#define NVOX (BDIM * DHW)           // 1179648

#define BIGF 1e10f
#define FINF 3.0e38f

// ---------------------------------------------------------------------------
// Kernel 1: init f_pos/f_neg from target and EDT pass along W (contiguous).
// 16 lines of 96 per block, 256 threads = 16 threads/line, 6 outputs/thread
// (strided by 16) so each LDS float4 read feeds 6 outputs. Line stride padded
// to 100 floats (100%32=4) so the 4 lines in a wave hit disjoint banks.
// ---------------------------------------------------------------------------
#define LSTR 100
__global__ __launch_bounds__(256) void edt_pass_w(const float* __restrict__ target,
                                                  float* __restrict__ fp,
                                                  float* __restrict__ fn,
                                                  float* __restrict__ acc) {
    __shared__ float sfp[16 * LSTR];
    __shared__ float sfn[16 * LSTR];
    const int tid  = threadIdx.x;
    const int base = blockIdx.x * (16 * WDIM);

    if (blockIdx.x == 0 && tid < 4) acc[tid] = 0.0f;  // consumed by kernel 3 (stream-ordered)

    for (int t = tid; t < 16 * WDIM; t += 256) {
        int l = t / WDIM;
        int i = t - l * WDIM;
        float tg = target[base + t];
        bool  m  = tg > 0.5f;
        sfp[l * LSTR + i] = m ? BIGF : 0.0f;
        sfn[l * LSTR + i] = m ? 0.0f : BIGF;
    }
    __syncthreads();

    const int c = tid & 15;          // lane within line
    const int l = tid >> 4;          // line 0..15
    const float4* rp = (const float4*)&sfp[l * LSTR];
    const float4* rn = (const float4*)&sfn[l * LSTR];

    float mp[6], mn[6];
    #pragma unroll
    for (int r = 0; r < 6; ++r) { mp[r] = FINF; mn[r] = FINF; }

    const float fc = (float)c;
    #pragma unroll 2
    for (int j4 = 0; j4 < WDIM / 4; ++j4) {
        float4 p = rp[j4];
        float4 n = rn[j4];
        float db = fc - (float)(4 * j4);   // d for r=0 at lane .x
        #pragma unroll
        for (int jj = 0; jj < 4; ++jj) {
            float pv = jj == 0 ? p.x : jj == 1 ? p.y : jj == 2 ? p.z : p.w;
            float nv = jj == 0 ? n.x : jj == 1 ? n.y : jj == 2 ? n.z : n.w;
            float d0 = db - (float)jj;
            #pragma unroll
            for (int r = 0; r < 6; ++r) {
                float d = d0 + (float)(16 * r);
                mp[r] = fminf(mp[r], fmaf(d, d, pv));
                mn[r] = fminf(mn[r], fmaf(d, d, nv));
            }
        }
    }
    #pragma unroll
    for (int r = 0; r < 6; ++r) {
        int g = base + l * WDIM + c + 16 * r;
        fp[g] = mp[r];
        fn[g] = mn[r];
    }
}

// ---------------------------------------------------------------------------
// Kernel 2: EDT pass along H. Tile = one (b,d) slab x 96 h x 32 w.
// grid = B*D*3. Thread owns float4-col q (0..7) and 3 rows {r0, r0+32, r0+64}:
// each LDS float4 read feeds 3 row-accumulators. In-place (tiles partition).
// ---------------------------------------------------------------------------
__global__ __launch_bounds__(256) void edt_pass_h(float* __restrict__ fp,
                                                  float* __restrict__ fn) {
    __shared__ float sfp[HDIM * 32];
    __shared__ float sfn[HDIM * 32];
    const int tid  = threadIdx.x;
    const int slab = blockIdx.x / 3;            // b*D + d
    const int w0   = (blockIdx.x % 3) * 32;
    const int base = slab * HW + w0;            // element (h, wi) -> base + h*W + wi

    for (int t = tid; t < HDIM * 32; t += 256) {
        int h = t >> 5, wi = t & 31;
        int g = base + h * WDIM + wi;
        sfp[t] = fp[g];
        sfn[t] = fn[g];
    }
    __syncthreads();

    const int q  = tid & 7;
    const int r0 = tid >> 3;                    // 0..31
    float4 mp[3], mn[3];
    #pragma unroll
    for (int k = 0; k < 3; ++k) {
        mp[k] = make_float4(FINF, FINF, FINF, FINF);
        mn[k] = make_float4(FINF, FINF, FINF, FINF);
    }
    const float4* rp = ((const float4*)sfp) + q;
    const float4* rn = ((const float4*)sfn) + q;

    float dd = (float)r0;
    #pragma unroll 2
    for (int j = 0; j < HDIM; ++j) {
        float4 p = rp[j * 8];
        float4 n = rn[j * 8];
        #pragma unroll
        for (int k = 0; k < 3; ++k) {
            float d  = dd + (float)(32 * k);
            float d2 = d * d;                   // exact integer in f32
            mp[k].x = fminf(mp[k].x, d2 + p.x);
            mp[k].y = fminf(mp[k].y, d2 + p.y);
            mp[k].z = fminf(mp[k].z, d2 + p.z);
            mp[k].w = fminf(mp[k].w, d2 + p.w);
            mn[k].x = fminf(mn[k].x, d2 + n.x);
            mn[k].y = fminf(mn[k].y, d2 + n.y);
            mn[k].z = fminf(mn[k].z, d2 + n.z);
            mn[k].w = fminf(mn[k].w, d2 + n.w);
        }
        dd -= 1.f;
    }
    #pragma unroll
    for (int k = 0; k < 3; ++k) {
        int g = base + (r0 + 32 * k) * WDIM + q * 4;
        *(float4*)&fp[g] = mp[k];
        *(float4*)&fn[g] = mn[k];
    }
}

// ---------------------------------------------------------------------------
// Kernel 3: EDT pass along D + fused loss epilogue + per-batch reduction.
// Tile = one (b,h) x 64 d x 32 w. grid = B*H*3. Thread owns q and 2 rows.
// ---------------------------------------------------------------------------
__device__ __forceinline__ void accum_loss(float mpv, float mnv, float p, float t,
                                           float& num, float& den) {
    float dp = sqrtf(mpv);
    float dn = sqrtf(mnv);
    float a  = fabsf(dn - dp);
    float w;
    if (a <= 3.0f)      w = 1.0f;
    else if (a >= 5.0f) w = 0.0f;
    else                w = 1.0f - (a - 3.0f) * 0.5f;
    float lp = fmaxf(logf(p), -100.0f);
    float l1 = fmaxf(logf(1.0f - p), -100.0f);
    float bce = -(t * lp + (1.0f - t) * l1);
    num += bce * w;
    den += w;
}

__global__ __launch_bounds__(256) void edt_pass_d_loss(const float* __restrict__ fp,
                                                       const float* __restrict__ fn,
                                                       const float* __restrict__ pred,
                                                       const float* __restrict__ target,
                                                       float* __restrict__ acc) {
    __shared__ float sfp[DDIM * 32];
    __shared__ float sfn[DDIM * 32];
    __shared__ float rsum[8];
    const int tid = threadIdx.x;
    const int w0  = (blockIdx.x % 3) * 32;
    const int bh  = blockIdx.x / 3;
    const int b   = bh / HDIM;
    const int h   = bh - b * HDIM;
    const int base = b * DHW + h * WDIM + w0;   // element (d, wi) -> base + d*HW + wi

    for (int t = tid; t < DDIM * 32; t += 256) {
        int d = t >> 5, wi = t & 31;
        int g = base + d * HW + wi;
        sfp[t] = fp[g];
        sfn[t] = fn[g];
    }
    __syncthreads();

    const int q  = tid & 7;
    const int r0 = tid >> 3;                    // 0..31; rows r0, r0+32
    float4 mp[2], mn[2];
    #pragma unroll
    for (int k = 0; k < 2; ++k) {
        mp[k] = make_float4(FINF, FINF, FINF, FINF);
        mn[k] = make_float4(FINF, FINF, FINF, FINF);
    }
    const float4* rp = ((const float4*)sfp) + q;
    const float4* rn = ((const float4*)sfn) + q;

    float dd = (float)r0;
    #pragma unroll 2
    for (int j = 0; j < DDIM; ++j) {
        float4 p = rp[j * 8];
        float4 n = rn[j * 8];
        #pragma unroll
        for (int k = 0; k < 2; ++k) {
            float d  = dd + (float)(32 * k);
            float d2 = d * d;
            mp[k].x = fminf(mp[k].x, d2 + p.x);
            mp[k].y = fminf(mp[k].y, d2 + p.y);
            mp[k].z = fminf(mp[k].z, d2 + p.z);
            mp[k].w = fminf(mp[k].w, d2 + p.w);
            mn[k].x = fminf(mn[k].x, d2 + n.x);
            mn[k].y = fminf(mn[k].y, d2 + n.y);
            mn[k].z = fminf(mn[k].z, d2 + n.z);
            mn[k].w = fminf(mn[k].w, d2 + n.w);
        }
        dd -= 1.f;
    }

    float num = 0.f, den = 0.f;
    #pragma unroll
    for (int k = 0; k < 2; ++k) {
        int g = base + (r0 + 32 * k) * HW + q * 4;
        float4 pr = *(const float4*)&pred[g];
        float4 tg = *(const float4*)&target[g];
        accum_loss(mp[k].x, mn[k].x, pr.x, tg.x, num, den);
        accum_loss(mp[k].y, mn[k].y, pr.y, tg.y, num, den);
        accum_loss(mp[k].z, mn[k].z, pr.z, tg.z, num, den);
        accum_loss(mp[k].w, mn[k].w, pr.w, tg.w, num, den);
    }

    // wave (64) reduce, then cross-wave via LDS, then one atomic pair per block
    for (int off = 32; off > 0; off >>= 1) {
        num += __shfl_down(num, off);
        den += __shfl_down(den, off);
    }
    if ((tid & 63) == 0) {
        rsum[tid >> 6]       = num;
        rsum[4 + (tid >> 6)] = den;
    }
    __syncthreads();
    if (tid == 0) {
        float ns = rsum[0] + rsum[1] + rsum[2] + rsum[3];
        float ds = rsum[4] + rsum[5] + rsum[6] + rsum[7];
        atomicAdd(&acc[b], ns);
        atomicAdd(&acc[2 + b], ds);
    }
}

// ---------------------------------------------------------------------------
// Kernel 4: finalize scalar
// ---------------------------------------------------------------------------
__global__ void finalize(const float* __restrict__ acc, float* __restrict__ out) {
    if (threadIdx.x == 0) {
        float r0 = acc[0] / (acc[2] + 1e-5f);
        float r1 = acc[1] / (acc[3] + 1e-5f);
        out[0] = 0.5f * (r0 + r1);
    }
}

extern "C" void kernel_launch(void* const* d_in, const int* in_sizes, int n_in,
                              void* d_out, int out_size, void* d_ws, size_t ws_size,
                              hipStream_t stream) {
    const float* pred   = (const float*)d_in[0];
    const float* target = (const float*)d_in[1];
    float* fp  = (float*)d_ws;          // NVOX floats
    float* fn  = fp + NVOX;             // NVOX floats
    float* acc = fn + NVOX;             // 4 floats: num[2], den[2]
    float* out = (float*)d_out;

    edt_pass_w<<<BDIM * DDIM * HDIM / 16, 256, 0, stream>>>(target, fp, fn, acc);
    edt_pass_h<<<BDIM * DDIM * 3, 256, 0, stream>>>(fp, fn);
    edt_pass_d_loss<<<BDIM * HDIM * 3, 256, 0, stream>>>(fp, fn, pred, target, acc);
    finalize<<<1, 64, 0, stream>>>(acc, out);
}